// Round 1
// baseline (760.063 us; speedup 1.0000x reference)
//
#include <hip/hip_runtime.h>

// GINEConv: out = (1+eps)*node_feat + segment_sum(relu(node_feat[src] + edge_feat), dst)
// N=50000, D=128, E=800000, fp32.
//
// R2: (a) scan_kernel rewritten thread-chunked: 2 barriers total instead of
//     ~49 barrier-ed carry-chained rounds (was a single-CU serial bottleneck).
//     (b) perm packed as int2 {src, eid}: one scattered 8B store in
//     scatter_perm, one 8B load per edge in aggregate.
//     (c) aggregate_kernel: half-wave float4 — lanes 0-31 take even edges,
//     lanes 32-63 odd edges, 16B/lane loads, unroll x2 (4 edges in flight),
//     cross-half __shfl_xor(.,32) reduce, lanes 0-31 write the row.

#define D 128

// ---------- fallback path (R0) ----------
__global__ void init_out_kernel(const float4* __restrict__ nf,
                                const float* __restrict__ eps,
                                float4* __restrict__ out, int n4) {
    int i = blockIdx.x * blockDim.x + threadIdx.x;
    if (i >= n4) return;
    float s = 1.0f + eps[0];
    float4 v = nf[i];
    v.x *= s; v.y *= s; v.z *= s; v.w *= s;
    out[i] = v;
}

__global__ void edge_scatter_kernel(const float4* __restrict__ nf,
                                    const float4* __restrict__ ef,
                                    const int* __restrict__ src,
                                    const int* __restrict__ dst,
                                    float* __restrict__ out, int E_) {
    int t = blockIdx.x * blockDim.x + threadIdx.x;
    int e = t >> 5;
    int c = t & 31;
    if (e >= E_) return;
    int s = src[e];
    int d = dst[e];
    float4 a = ef[(size_t)e * 32 + c];
    float4 b = nf[(size_t)s * 32 + c];
    float4 m;
    m.x = fmaxf(a.x + b.x, 0.0f);
    m.y = fmaxf(a.y + b.y, 0.0f);
    m.z = fmaxf(a.z + b.z, 0.0f);
    m.w = fmaxf(a.w + b.w, 0.0f);
    float* o = out + (size_t)d * D + c * 4;
    atomicAdd(o + 0, m.x);
    atomicAdd(o + 1, m.y);
    atomicAdd(o + 2, m.z);
    atomicAdd(o + 3, m.w);
}

// ---------- CSR build ----------
__global__ void histogram_kernel(const int* __restrict__ dst, int* __restrict__ deg, int E_) {
    int e = blockIdx.x * blockDim.x + threadIdx.x;
    if (e >= E_) return;
    atomicAdd(&deg[dst[e]], 1);
}

// Single-block exclusive scan over n counts, thread-chunked:
// each thread owns a contiguous ceil(n/1024) run. Phase 1: local sum.
// Phase 2: ONE block scan of the 1024 sums. Phase 3: local prefix write.
// Only 2 __syncthreads total (vs ~150 in R1's carry-chained version).
// deg may alias cursor: threads only touch their own chunk, and each
// element is read before written within the same thread.
__global__ void scan_kernel(const int* __restrict__ deg, int* __restrict__ offs,
                            int* __restrict__ cursor, int n) {
    __shared__ int wsum[16];
    int t = threadIdx.x;
    int lane = t & 63;
    int w = t >> 6;
    int chunk = (n + 1023) >> 10;
    int begin = t * chunk; if (begin > n) begin = n;
    int endi = begin + chunk; if (endi > n) endi = n;

    int s = 0;
    for (int i = begin; i < endi; ++i) s += deg[i];

    // wave-inclusive scan of per-thread sums
    int v = s;
    #pragma unroll
    for (int off = 1; off < 64; off <<= 1) {
        int u = __shfl_up(v, off);
        if (lane >= off) v += u;
    }
    if (lane == 63) wsum[w] = v;
    __syncthreads();
    if (t == 0) {
        int r = 0;
        #pragma unroll
        for (int i = 0; i < 16; ++i) { int tv = wsum[i]; wsum[i] = r; r += tv; }
    }
    __syncthreads();

    int run = wsum[w] + v - s;     // exclusive prefix for this thread's chunk
    for (int i = begin; i < endi; ++i) {
        int d = deg[i];            // read (possibly aliased) before write
        offs[i] = run;
        cursor[i] = run;
        run += d;
    }
    if (t == 1023) offs[n] = run;  // t=1023's chunk is empty/last -> run = total
}

__global__ void scatter_perm_kernel(const int* __restrict__ src, const int* __restrict__ dst,
                                    int* __restrict__ cursor,
                                    int2* __restrict__ perm, int E_) {
    int e = blockIdx.x * blockDim.x + threadIdx.x;
    if (e >= E_) return;
    int d = dst[e];
    int pos = atomicAdd(&cursor[d], 1);
    perm[pos] = make_int2(src[e], e);
}

// ---------- aggregation: one wave per destination node, half-wave float4 ----------
__global__ void aggregate_kernel(const float4* __restrict__ nf,
                                 const float4* __restrict__ ef,
                                 const int* __restrict__ offs,
                                 const int2* __restrict__ perm,
                                 const float* __restrict__ eps,
                                 float4* __restrict__ out, int n) {
    int wid = (blockIdx.x * blockDim.x + threadIdx.x) >> 6;
    if (wid >= n) return;
    int lane = threadIdx.x & 63;
    int half = lane >> 5;          // 0: even edges, 1: odd edges
    int col  = lane & 31;          // float4 column within the 128-float row

    int start = offs[wid];
    int end   = offs[wid + 1];

    float accx = 0.0f, accy = 0.0f, accz = 0.0f, accw = 0.0f;

    int i = start + half;
    for (; i + 2 < end; i += 4) {
        int2 p0 = perm[i];
        int2 p1 = perm[i + 2];
        float4 a0 = ef[(size_t)p0.y * 32 + col];
        float4 b0 = nf[(size_t)p0.x * 32 + col];
        float4 a1 = ef[(size_t)p1.y * 32 + col];
        float4 b1 = nf[(size_t)p1.x * 32 + col];
        accx += fmaxf(a0.x + b0.x, 0.0f) + fmaxf(a1.x + b1.x, 0.0f);
        accy += fmaxf(a0.y + b0.y, 0.0f) + fmaxf(a1.y + b1.y, 0.0f);
        accz += fmaxf(a0.z + b0.z, 0.0f) + fmaxf(a1.z + b1.z, 0.0f);
        accw += fmaxf(a0.w + b0.w, 0.0f) + fmaxf(a1.w + b1.w, 0.0f);
    }
    for (; i < end; i += 2) {
        int2 p0 = perm[i];
        float4 a0 = ef[(size_t)p0.y * 32 + col];
        float4 b0 = nf[(size_t)p0.x * 32 + col];
        accx += fmaxf(a0.x + b0.x, 0.0f);
        accy += fmaxf(a0.y + b0.y, 0.0f);
        accz += fmaxf(a0.z + b0.z, 0.0f);
        accw += fmaxf(a0.w + b0.w, 0.0f);
    }

    // cross-half reduce: lane l gets partner l^32's accumulator
    accx += __shfl_xor(accx, 32);
    accy += __shfl_xor(accy, 32);
    accz += __shfl_xor(accz, 32);
    accw += __shfl_xor(accw, 32);

    if (half == 0) {
        float sc = 1.0f + eps[0];
        float4 self = nf[(size_t)wid * 32 + col];
        float4 o;
        o.x = sc * self.x + accx;
        o.y = sc * self.y + accy;
        o.z = sc * self.z + accz;
        o.w = sc * self.w + accw;
        out[(size_t)wid * 32 + col] = o;
    }
}

extern "C" void kernel_launch(void* const* d_in, const int* in_sizes, int n_in,
                              void* d_out, int out_size, void* d_ws, size_t ws_size,
                              hipStream_t stream) {
    const float* node_feat = (const float*)d_in[0];
    const int*   edge_index = (const int*)d_in[1];
    const float* edge_feat = (const float*)d_in[2];
    const float* eps = (const float*)d_in[3];
    float* out = (float*)d_out;

    int ND = in_sizes[0];
    int N_ = ND / D;
    int E_ = in_sizes[1] / 2;
    const int* src = edge_index;
    const int* dst = edge_index + E_;

    size_t need = ((size_t)2 * N_ + 2) * sizeof(int) + (size_t)E_ * sizeof(int2);
    if (ws_size < need) {
        // fallback: R0 atomic path
        int n4 = ND / 4;
        init_out_kernel<<<(n4 + 255) / 256, 256, 0, stream>>>(
            (const float4*)node_feat, eps, (float4*)out, n4);
        long long total = (long long)E_ * 32;
        int g2 = (int)((total + 255) / 256);
        edge_scatter_kernel<<<g2, 256, 0, stream>>>(
            (const float4*)node_feat, (const float4*)edge_feat, src, dst, out, E_);
        return;
    }

    int* cursor = (int*)d_ws;            // N ints (also deg histogram)
    int* offs   = cursor + N_;           // N+1 ints (+1 pad for int2 alignment)
    int2* perm  = (int2*)(offs + (N_ + 2)); // E int2, 8B-aligned

    // 1. zero the histogram
    hipMemsetAsync(cursor, 0, (size_t)N_ * sizeof(int), stream);
    // 2. histogram of dst
    histogram_kernel<<<(E_ + 255) / 256, 256, 0, stream>>>(dst, cursor, E_);
    // 3. exclusive scan -> offs, cursor
    scan_kernel<<<1, 1024, 0, stream>>>(cursor, offs, cursor, N_);
    // 4. scatter packed (src, eid) into CSR order
    scatter_perm_kernel<<<(E_ + 255) / 256, 256, 0, stream>>>(
        src, dst, cursor, perm, E_);
    // 5. aggregate: one wave per node, half-wave float4, single coalesced write
    int waves_per_block = 4;             // 256 threads
    int g = (N_ + waves_per_block - 1) / waves_per_block;
    aggregate_kernel<<<g, 256, 0, stream>>>(
        (const float4*)node_feat, (const float4*)edge_feat,
        offs, perm, eps, (float4*)out, N_);
}